// Round 6
// baseline (30.678 us; speedup 1.0000x reference)
//
#include <hip/hip_runtime.h>

// QuantHotLowRank: out[n][d] = sum_r Uq[ids[n]][r] * Bq[r][d]
// K=200000, R=64, D=1024, N=16384, 4-bit groupwise fake-quant, group=32.
//
// Pipeline (2 kernels):
//   1) quant_fused: one launch covering both
//        - B [64,1024] -> Bq^T split-bf16 planes [1024][64] (hi,lo) in ws
//        - gather+quantize the 16384 selected U rows -> Uq planes [16384][64]
//      Quant decisions in FP64 to bit-match the numpy-fp64 reference
//      (fp32 flips levels at w/scale ~ n+.5 -> absmax 1.06; fp64 -> 0.25).
//   2) gemm: B tile LDS-staged (shared by 4 waves), split-bf16 MFMA
//      (hi*hi + hi*lo + lo*hi, exact to ~2^-18), LDS-transposed coalesced
//      dwordx4 NON-TEMPORAL stores (out is write-once; keep L2 for Bq/Uq).

#define R_DIM 64
#define D_DIM 1024
#define N_IDS 16384

#define BM 64          // rows per block (4 waves x 16)
#define BN 128         // cols per block
#define LDS_STRIDE 72  // ushorts per B-LDS row: 64 + 8 pad (kills bank conflicts)
#define OT_STRIDE 132  // floats per out-LDS row: 128 + 4 pad

#define NB_QB 256      // quant blocks for B   (65536 / 256)
#define NB_QU 4096     // quant blocks for U   (16384*64 / 256)

typedef __attribute__((ext_vector_type(8))) __bf16 bf16x8;
typedef __attribute__((ext_vector_type(4))) float f32x4;

__device__ inline unsigned short f32_to_bf16_rne(float f) {
  union { float f; unsigned int u; } c; c.f = f;
  unsigned int u = c.u;
  u += 0x7fffu + ((u >> 16) & 1u);   // round-to-nearest-even (finite inputs only)
  return (unsigned short)(u >> 16);
}

__device__ inline float bf16_bits_to_f32(unsigned short h) {
  union { unsigned int u; float f; } c; c.u = ((unsigned int)h) << 16;
  return c.f;
}

// fp64 fake-quant matching numpy bit-exactly; w and group-amax a are fp32.
__device__ inline void quant_split(float w, float a, unsigned short* hi, unsigned short* lo) {
  double amax  = fmax((double)a, 1e-8);
  double scale = amax / 7.0;                       // q_max = (1<<(4-1))-1 = 7
  double t     = (double)w / scale;
  double q     = fmin(fmax(rint(t), -7.0), 7.0) * scale;
  float qf = (float)q;
  unsigned short h = f32_to_bf16_rne(qf);
  *hi = h;
  *lo = f32_to_bf16_rne(qf - bf16_bits_to_f32(h));
}

// group-of-32 amax via shuffles (groups are 32 consecutive lanes)
__device__ inline float group_amax32(float w) {
  float a = fabsf(w);
  a = fmaxf(a, __shfl_xor(a, 1));
  a = fmaxf(a, __shfl_xor(a, 2));
  a = fmaxf(a, __shfl_xor(a, 4));
  a = fmaxf(a, __shfl_xor(a, 8));
  a = fmaxf(a, __shfl_xor(a, 16));
  return a;
}

// ---------------- Kernel 1: fused quantize of B and gathered U --------------
__global__ __launch_bounds__(256) void quant_fused_kernel(
    const float* __restrict__ U, const float* __restrict__ B,
    const int* __restrict__ ids,
    unsigned short* __restrict__ BqT_hi, unsigned short* __restrict__ BqT_lo,
    unsigned short* __restrict__ Uq_hi,  unsigned short* __restrict__ Uq_lo) {
  const int bid = blockIdx.x;
  if (bid < NB_QB) {
    // --- B plane: e over [0, 64*1024), groups of 32 along D ---
    int e = bid * 256 + threadIdx.x;
    int r = e >> 10;
    int c = e & 1023;
    float w = B[e];
    unsigned short hi, lo;
    quant_split(w, group_amax32(w), &hi, &lo);
    BqT_hi[c * R_DIM + r] = hi;
    BqT_lo[c * R_DIM + r] = lo;
  } else {
    // --- U plane: e over [0, N_IDS*64); one row per 64-lane wave ---
    int e = (bid - NB_QB) * 256 + threadIdx.x;
    int n = e >> 6;
    int r = e & 63;
    // read-once gathered row: non-temporal, don't pollute L2 (Uq/Bq live there)
    float w = __builtin_nontemporal_load(&U[(size_t)ids[n] * R_DIM + r]);
    unsigned short hi, lo;
    quant_split(w, group_amax32(w), &hi, &lo);
    Uq_hi[e] = hi;
    Uq_lo[e] = lo;
  }
}

// ---------------- Kernel 2: split-bf16 MFMA GEMM + nt coalesced stores ------
__global__ __launch_bounds__(256) void gemm_kernel(
    const unsigned short* __restrict__ Uq_hi, const unsigned short* __restrict__ Uq_lo,
    const unsigned short* __restrict__ BqT_hi, const unsigned short* __restrict__ BqT_lo,
    float* __restrict__ out) {
  // B tiles (2 planes, 18KB each) first; reused as the fp32 out-transpose
  // buffer (33KB) after the MFMA phase. 36864B total -> 4 blocks/CU.
  __shared__ char smem[2 * BN * LDS_STRIDE * 2];
  unsigned short* bt_hi = (unsigned short*)smem;
  unsigned short* bt_lo = bt_hi + BN * LDS_STRIDE;
  float* ot = (float*)smem;                          // 4 waves x 16 x 132 floats

  const int tid  = threadIdx.x;
  const int lane = tid & 63;
  const int wave = tid >> 6;
  const int bx   = blockIdx.x;
  const int nb   = bx & 7;     // 8 col-blocks (== XCD id under %8 round-robin:
  const int mb   = bx >> 3;    //  each XCD keeps its own 64KB B-slice L2-hot)
  const int n0   = nb * BN;

  // --- stage Bq^T tiles (rows n0..n0+127 = one contiguous 16KB span each) ---
  {
    const uint4* src_hi = (const uint4*)(BqT_hi + (size_t)n0 * R_DIM);
    const uint4* src_lo = (const uint4*)(BqT_lo + (size_t)n0 * R_DIM);
    #pragma unroll
    for (int it = 0; it < 4; ++it) {
      int c = tid + it * 256;            // 16B chunk index, 0..1023
      int row = c >> 3, off = c & 7;
      *(uint4*)&bt_hi[row * LDS_STRIDE + off * 8] = src_hi[c];
      *(uint4*)&bt_lo[row * LDS_STRIDE + off * 8] = src_lo[c];
    }
  }

  // --- load this wave's A fragments from the precomputed Uq planes ---
  const int m0    = mb * BM + wave * 16;
  const int arow  = m0 + (lane & 15);
  const int koff  = (lane >> 4) * 8;         // k-chunk of 8 within the 32-group
  const int nlane = lane & 15;

  bf16x8 afrag_hi[2], afrag_lo[2];
  #pragma unroll
  for (int s = 0; s < 2; ++s) {
    afrag_hi[s] = *(const bf16x8*)&Uq_hi[(size_t)arow * R_DIM + s * 32 + koff];
    afrag_lo[s] = *(const bf16x8*)&Uq_lo[(size_t)arow * R_DIM + s * 32 + koff];
  }

  __syncthreads();

  // --- MFMA: 8 n-frags x 2 k-steps x {hi*hi, hi*lo, lo*hi} ---
  f32x4 acc[8];
  #pragma unroll
  for (int nf = 0; nf < 8; ++nf) acc[nf] = (f32x4){0.f, 0.f, 0.f, 0.f};

  #pragma unroll
  for (int nf = 0; nf < 8; ++nf) {
    #pragma unroll
    for (int s = 0; s < 2; ++s) {
      const int boff = (nf * 16 + nlane) * LDS_STRIDE + s * 32 + koff;
      union { uint4 u; bf16x8 b; } bh, bl;
      bh.u = *(const uint4*)&bt_hi[boff];
      bl.u = *(const uint4*)&bt_lo[boff];
      acc[nf] = __builtin_amdgcn_mfma_f32_16x16x32_bf16(afrag_hi[s], bh.b, acc[nf], 0, 0, 0);
      acc[nf] = __builtin_amdgcn_mfma_f32_16x16x32_bf16(afrag_hi[s], bl.b, acc[nf], 0, 0, 0);
      acc[nf] = __builtin_amdgcn_mfma_f32_16x16x32_bf16(afrag_lo[s], bh.b, acc[nf], 0, 0, 0);
    }
  }

  __syncthreads();   // everyone done reading B tiles; reuse smem for out

  // --- transpose via LDS: frag layout -> row-major, per-wave region ---
  float* w = ot + wave * 16 * OT_STRIDE;
  {
    const int r0 = (lane >> 4) << 2;           // 0,4,8,12
    #pragma unroll
    for (int nf = 0; nf < 8; ++nf) {
      #pragma unroll
      for (int i = 0; i < 4; ++i) {
        // bank = ((r0+i)*4 + nlane + 16nf) % 32 -> 2 lanes/bank: free
        w[(r0 + i) * OT_STRIDE + nlane + nf * 16] = acc[nf][i];
      }
    }
  }
  // same-wave RAW on LDS: compiler inserts lgkmcnt; no cross-wave sharing.
  #pragma unroll
  for (int j = 0; j < 8; ++j) {
    const int row = j * 2 + (lane >> 5);       // 0..15
    f32x4 v = *(const f32x4*)&w[row * OT_STRIDE + (lane & 31) * 4];
    // 32 lanes x 16B = one contiguous 512B row segment; 2 rows per inst.
    // NON-TEMPORAL: out is write-once, never re-read -> don't evict Bq/Uq
    // from L2 with 64MB of write-back stream. (clang ext_vector type, not
    // HIP_vector_type float4 -- the builtin rejects the latter.)
    __builtin_nontemporal_store(v,
        (f32x4*)&out[(size_t)(m0 + row) * D_DIM + n0 + (lane & 31) * 4]);
  }
}

extern "C" void kernel_launch(void* const* d_in, const int* in_sizes, int n_in,
                              void* d_out, int out_size, void* d_ws, size_t ws_size,
                              hipStream_t stream) {
  const float* U   = (const float*)d_in[0];
  const float* B   = (const float*)d_in[1];
  const int*   ids = (const int*)d_in[2];
  float* out = (float*)d_out;

  unsigned short* BqT_hi = (unsigned short*)d_ws;                       // 128 KB
  unsigned short* BqT_lo = BqT_hi + R_DIM * D_DIM;                      // 128 KB
  unsigned short* Uq_hi  = BqT_lo + R_DIM * D_DIM;                      // 2 MB
  unsigned short* Uq_lo  = Uq_hi + (size_t)N_IDS * R_DIM;               // 2 MB

  quant_fused_kernel<<<NB_QB + NB_QU, 256, 0, stream>>>(U, B, ids, BqT_hi, BqT_lo, Uq_hi, Uq_lo);
  gemm_kernel<<<(N_IDS / BM) * (D_DIM / BN), 256, 0, stream>>>(Uq_hi, Uq_lo, BqT_hi, BqT_lo, out);
}

// Round 7
// 27.292 us; speedup vs baseline: 1.1241x; 1.1241x over previous
//
#include <hip/hip_runtime.h>

// QuantHotLowRank: out[n][d] = sum_r Uq[ids[n]][r] * Bq[r][d]
// K=200000, R=64, D=1024, N=16384, 4-bit groupwise fake-quant, group=32.
//
// Pipeline (2 kernels):
//   1) quantB: B [64,1024] -> Bq^T split-bf16 planes [1024][64] (hi,lo) in ws.
//   2) gemm:   gather + fp64-quantize A rows IN-REGISTER (fragment-aligned
//              distribution, amax via shfl_xor 16/32 over the 32-elem group),
//              B tile LDS-staged, split-bf16 MFMA (hi*hi + hi*lo + lo*hi,
//              exact to ~2^-18), LDS-transposed coalesced nt stores.
//      No Uq round-trip through HBM (R6 wrote 8.5MB then re-read 8MB).
//
// Quant decisions in FP64 to bit-match the numpy-fp64 reference (fp32 flips
// levels at w/scale ~ n+.5 -> absmax 1.06; fp64 -> 0.25 = split-bf16 noise).

#define R_DIM 64
#define D_DIM 1024
#define N_IDS 16384

#define BM 64          // rows per block (4 waves x 16)
#define BN 128         // cols per block
#define LDS_STRIDE 72  // ushorts per B-LDS row: 64 + 8 pad (kills bank conflicts)
#define OT_STRIDE 132  // floats per out-LDS row: 128 + 4 pad

typedef __attribute__((ext_vector_type(8))) __bf16 bf16x8;
typedef __attribute__((ext_vector_type(4))) float f32x4;

__device__ inline unsigned short f32_to_bf16_rne(float f) {
  union { float f; unsigned int u; } c; c.f = f;
  unsigned int u = c.u;
  u += 0x7fffu + ((u >> 16) & 1u);   // round-to-nearest-even (finite inputs only)
  return (unsigned short)(u >> 16);
}

__device__ inline float bf16_bits_to_f32(unsigned short h) {
  union { unsigned int u; float f; } c; c.u = ((unsigned int)h) << 16;
  return c.f;
}

// fp64 fake-quant matching numpy bit-exactly; w and group-amax a are fp32.
__device__ inline void quant_split(float w, float a, unsigned short* hi, unsigned short* lo) {
  double amax  = fmax((double)a, 1e-8);
  double scale = amax / 7.0;                       // q_max = (1<<(4-1))-1 = 7
  double t     = (double)w / scale;
  double q     = fmin(fmax(rint(t), -7.0), 7.0) * scale;
  float qf = (float)q;
  unsigned short h = f32_to_bf16_rne(qf);
  *hi = h;
  *lo = f32_to_bf16_rne(qf - bf16_bits_to_f32(h));
}

// ---------------- Kernel 1: quantize B -> split Bq^T (bf16 hi/lo planes) ----
__global__ __launch_bounds__(256) void quantB_kernel(
    const float* __restrict__ B,
    unsigned short* __restrict__ BqT_hi, unsigned short* __restrict__ BqT_lo) {
  int e = blockIdx.x * 256 + threadIdx.x;    // 0..65535
  int r = e >> 10;                           // row in [0,64)
  int c = e & 1023;                          // col in [0,1024)
  float w = B[e];
  float a = fabsf(w);
  a = fmaxf(a, __shfl_xor(a, 1));
  a = fmaxf(a, __shfl_xor(a, 2));
  a = fmaxf(a, __shfl_xor(a, 4));
  a = fmaxf(a, __shfl_xor(a, 8));
  a = fmaxf(a, __shfl_xor(a, 16));
  unsigned short hi, lo;
  quant_split(w, a, &hi, &lo);
  BqT_hi[c * R_DIM + r] = hi;
  BqT_lo[c * R_DIM + r] = lo;
}

// ---------------- Kernel 2: gather+quant A in-register, MFMA, nt stores -----
__global__ __launch_bounds__(256) void gemm_kernel(
    const float* __restrict__ U, const int* __restrict__ ids,
    const unsigned short* __restrict__ BqT_hi, const unsigned short* __restrict__ BqT_lo,
    float* __restrict__ out) {
  // B tiles (2 planes, 18KB each) first; reused as the fp32 out-transpose
  // buffer (33KB) after the MFMA phase. 36864B total -> 4 blocks/CU.
  __shared__ char smem[2 * BN * LDS_STRIDE * 2];
  unsigned short* bt_hi = (unsigned short*)smem;
  unsigned short* bt_lo = bt_hi + BN * LDS_STRIDE;
  float* ot = (float*)smem;                          // 4 waves x 16 x 132 floats

  const int tid  = threadIdx.x;
  const int lane = tid & 63;
  const int wave = tid >> 6;
  const int bx   = blockIdx.x;
  const int nb   = bx & 7;     // 8 col-blocks (== XCD id under %8 round-robin)
  const int mb   = bx >> 3;
  const int n0   = nb * BN;

  // --- stage Bq^T tiles (rows n0..n0+127 = one contiguous 16KB span each) ---
  {
    const uint4* src_hi = (const uint4*)(BqT_hi + (size_t)n0 * R_DIM);
    const uint4* src_lo = (const uint4*)(BqT_lo + (size_t)n0 * R_DIM);
    #pragma unroll
    for (int it = 0; it < 4; ++it) {
      int c = tid + it * 256;            // 16B chunk index, 0..1023
      int row = c >> 3, off = c & 7;
      *(uint4*)&bt_hi[row * LDS_STRIDE + off * 8] = src_hi[c];
      *(uint4*)&bt_lo[row * LDS_STRIDE + off * 8] = src_lo[c];
    }
  }

  // --- gather + fp64-quantize this wave's 16 A rows, fully in-register ---
  // Fragment-aligned distribution: lane holds elems s*32+koff..+8 of row
  // (lane&15); the 4 lanes {lane&15 fixed, lane>>4 varying} hold exactly
  // one 32-elem quant group -> amax = local8 + shfl_xor(16) + shfl_xor(32).
  const int m0    = mb * BM + wave * 16;
  const int rowid = ids[m0 + (lane & 15)];
  const int koff  = (lane >> 4) * 8;
  const int nlane = lane & 15;
  const float* urow = U + (size_t)rowid * R_DIM;

  bf16x8 afrag_hi[2], afrag_lo[2];
  #pragma unroll
  for (int s = 0; s < 2; ++s) {               // 2 quant groups == 2 MFMA k-steps
    float4 w0 = *(const float4*)(urow + s * 32 + koff);
    float4 w1 = *(const float4*)(urow + s * 32 + koff + 4);
    float wv[8] = {w0.x, w0.y, w0.z, w0.w, w1.x, w1.y, w1.z, w1.w};
    float a = 0.0f;
    #pragma unroll
    for (int j = 0; j < 8; ++j) a = fmaxf(a, fabsf(wv[j]));
    a = fmaxf(a, __shfl_xor(a, 16));
    a = fmaxf(a, __shfl_xor(a, 32));
    union { unsigned short s8[8]; bf16x8 b; } uh, ul;
    #pragma unroll
    for (int j = 0; j < 8; ++j) {
      unsigned short hi, lo;
      quant_split(wv[j], a, &hi, &lo);
      uh.s8[j] = hi;
      ul.s8[j] = lo;
    }
    afrag_hi[s] = uh.b;
    afrag_lo[s] = ul.b;
  }

  __syncthreads();

  // --- MFMA: 8 n-frags x 2 k-steps x {hi*hi, hi*lo, lo*hi} ---
  f32x4 acc[8];
  #pragma unroll
  for (int nf = 0; nf < 8; ++nf) acc[nf] = (f32x4){0.f, 0.f, 0.f, 0.f};

  #pragma unroll
  for (int nf = 0; nf < 8; ++nf) {
    #pragma unroll
    for (int s = 0; s < 2; ++s) {
      const int boff = (nf * 16 + nlane) * LDS_STRIDE + s * 32 + koff;
      union { uint4 u; bf16x8 b; } bh, bl;
      bh.u = *(const uint4*)&bt_hi[boff];
      bl.u = *(const uint4*)&bt_lo[boff];
      acc[nf] = __builtin_amdgcn_mfma_f32_16x16x32_bf16(afrag_hi[s], bh.b, acc[nf], 0, 0, 0);
      acc[nf] = __builtin_amdgcn_mfma_f32_16x16x32_bf16(afrag_hi[s], bl.b, acc[nf], 0, 0, 0);
      acc[nf] = __builtin_amdgcn_mfma_f32_16x16x32_bf16(afrag_lo[s], bh.b, acc[nf], 0, 0, 0);
    }
  }

  __syncthreads();   // everyone done reading B tiles; reuse smem for out

  // --- transpose via LDS: frag layout -> row-major, per-wave region ---
  float* w = ot + wave * 16 * OT_STRIDE;
  {
    const int r0 = (lane >> 4) << 2;           // 0,4,8,12
    #pragma unroll
    for (int nf = 0; nf < 8; ++nf) {
      #pragma unroll
      for (int i = 0; i < 4; ++i) {
        w[(r0 + i) * OT_STRIDE + nlane + nf * 16] = acc[nf][i];
      }
    }
  }
  #pragma unroll
  for (int j = 0; j < 8; ++j) {
    const int row = j * 2 + (lane >> 5);       // 0..15
    f32x4 v = *(const f32x4*)&w[row * OT_STRIDE + (lane & 31) * 4];
    // 32 lanes x 16B = one contiguous 512B row segment; nt: write-once stream
    __builtin_nontemporal_store(v,
        (f32x4*)&out[(size_t)(m0 + row) * D_DIM + n0 + (lane & 31) * 4]);
  }
}

extern "C" void kernel_launch(void* const* d_in, const int* in_sizes, int n_in,
                              void* d_out, int out_size, void* d_ws, size_t ws_size,
                              hipStream_t stream) {
  const float* U   = (const float*)d_in[0];
  const float* B   = (const float*)d_in[1];
  const int*   ids = (const int*)d_in[2];
  float* out = (float*)d_out;

  unsigned short* BqT_hi = (unsigned short*)d_ws;                       // 128 KB
  unsigned short* BqT_lo = BqT_hi + R_DIM * D_DIM;                      // 128 KB

  quantB_kernel<<<(R_DIM * D_DIM) / 256, 256, 0, stream>>>(B, BqT_hi, BqT_lo);
  gemm_kernel<<<(N_IDS / BM) * (D_DIM / BN), 256, 0, stream>>>(U, ids, BqT_hi, BqT_lo, out);
}